// Round 5
// baseline (266.307 us; speedup 1.0000x reference)
//
#include <hip/hip_runtime.h>

// MHA forward, MI355X/gfx950, bf16 MFMA pipeline. Round 5.
// x:[2,2048,1024] f32; w_q/k/v/o:[1024,1024] f32 (nn.Linear: y = x @ W^T)
// out:[2,2048,1024] f32.
//
// R5 = R4 with the actual bug fixed: PPAD was 40 (pad for a 32-wide row)
// while P rows are 64 keys wide -> P writes at col>=40 smashed the next row
// and wave3 ran past Psm. PPAD=72 now (64+8, same as KPAD). The R4 wave-local
// fence is kept: the P LDS round-trip is cross-lane, so compiler ordering is
// pinned with a memory-clobber asm (DS ops within a wave complete in order).

typedef __bf16 bf16x8 __attribute__((ext_vector_type(8)));
typedef float f32x4 __attribute__((ext_vector_type(4)));
typedef unsigned short u16;

#define S_LEN 2048
#define NH 16
#define DHD 64
#define KPAD 72   // u16 stride for Ksm/Vsm rows (64 cols + 8 pad, 144 B)
#define PPAD 72   // u16 stride for Psm rows (64 cols + 8 pad) — R3/R4 bug: was 40

__device__ __forceinline__ u16 f2bf(float f) {
  unsigned u = __float_as_uint(f);
  u += 0x7fffu + ((u >> 16) & 1u);  // RNE
  return (u16)(u >> 16);
}
__device__ __forceinline__ u16 f2bf_fast(float f) {  // round-half-up
  return (u16)((__float_as_uint(f) + 0x8000u) >> 16);
}

// wave-local LDS write->read ordering fence (cross-lane exchange within wave)
__device__ __forceinline__ void lds_wave_fence() {
  __builtin_amdgcn_wave_barrier();
  asm volatile("s_waitcnt lgkmcnt(0)" ::: "memory");
  __builtin_amdgcn_wave_barrier();
}

__device__ __forceinline__ void gld_lds16(const void* g, void* l) {
  __builtin_amdgcn_global_load_lds(
      (const __attribute__((address_space(1))) void*)g,
      (__attribute__((address_space(3))) void*)l, 16, 0, 0);
}

// ---------------- fp32 -> bf16 convert, all 5 tensors ----------------------
__global__ __launch_bounds__(256) void cvt_all(const float* __restrict__ x,
                                               const float* __restrict__ wq,
                                               const float* __restrict__ wk,
                                               const float* __restrict__ wv,
                                               const float* __restrict__ wo,
                                               u16* __restrict__ dst) {
  const int i = (blockIdx.x * 256 + threadIdx.x) * 4;
  const float* src;
  int off;
  if (i < (4 << 20))      { src = x;  off = 0; }
  else if (i < (5 << 20)) { src = wq; off = 4 << 20; }
  else if (i < (6 << 20)) { src = wk; off = 5 << 20; }
  else if (i < (7 << 20)) { src = wv; off = 6 << 20; }
  else                    { src = wo; off = 7 << 20; }
  const float4 v = *(const float4*)(src + (i - off));
  *(ushort4*)(dst + i) = make_ushort4(f2bf(v.x), f2bf(v.y), f2bf(v.z), f2bf(v.w));
}

// ---------------- fused QKV projection GEMM --------------------------------
__global__ __launch_bounds__(256) void gemm_qkv(const u16* __restrict__ A,
                                                const u16* __restrict__ Wq,
                                                const u16* __restrict__ Wk,
                                                const u16* __restrict__ Wv,
                                                u16* __restrict__ Qo,
                                                u16* __restrict__ Ko,
                                                u16* __restrict__ Vo) {
  constexpr int K = 1024;
  __shared__ __align__(16) u16 Asm[128 * 32];
  __shared__ __align__(16) u16 Bsm[128 * 32];
  const int tid = threadIdx.x;
  const int wave = tid >> 6, lane = tid & 63;
  const int wm = wave >> 1, wn = wave & 1;
  const int quad = lane >> 4, l16 = lane & 15;
  const int m0 = blockIdx.y * 128;
  const int n0g = blockIdx.x * 128;
  const int wsel = n0g >> 10, n0 = n0g & 1023;
  const u16* Bw = (wsel == 0) ? Wq : (wsel == 1 ? Wk : Wv);
  u16* out = (wsel == 0) ? Qo : (wsel == 1 ? Ko : Vo);

  const u16* Ag = A + (size_t)(m0 + (lane >> 2)) * K + (lane & 3) * 8;
  const u16* Bg = Bw + (size_t)(n0 + (lane >> 2)) * K + (lane & 3) * 8;

  f32x4 acc[4][4] = {};
  for (int k0 = 0; k0 < K; k0 += 32) {
#pragma unroll
    for (int c = 0; c < 2; ++c) {
      const int rbase = wave * 32 + c * 16;
      gld_lds16(Ag + (size_t)rbase * K + k0, Asm + rbase * 32);
      gld_lds16(Bg + (size_t)rbase * K + k0, Bsm + rbase * 32);
    }
    __syncthreads();
    bf16x8 af[4], bfv[4];
#pragma unroll
    for (int i = 0; i < 4; ++i)
      af[i] = *(const bf16x8*)(Asm + (wm * 64 + i * 16 + l16) * 32 + quad * 8);
#pragma unroll
    for (int j = 0; j < 4; ++j)
      bfv[j] = *(const bf16x8*)(Bsm + (wn * 64 + j * 16 + l16) * 32 + quad * 8);
#pragma unroll
    for (int i = 0; i < 4; ++i)
#pragma unroll
      for (int j = 0; j < 4; ++j)
        acc[i][j] = __builtin_amdgcn_mfma_f32_16x16x32_bf16(af[i], bfv[j],
                                                            acc[i][j], 0, 0, 0);
    __syncthreads();
  }

  if (wsel < 2) {
#pragma unroll
    for (int i = 0; i < 4; ++i)
#pragma unroll
      for (int j = 0; j < 4; ++j)
#pragma unroll
        for (int r = 0; r < 4; ++r) {
          const int m = m0 + wm * 64 + i * 16 + quad * 4 + r;
          const int n = n0 + wn * 64 + j * 16 + l16;
          const int b = m >> 11, s = m & 2047;
          const int h = n >> 6, dh = n & 63;
          out[(((size_t)(b * NH + h)) * S_LEN + s) * DHD + dh] =
              f2bf(acc[i][j][r]);
        }
  } else {
    // V^T: pack 4 consecutive s into one ushort4 store
#pragma unroll
    for (int i = 0; i < 4; ++i)
#pragma unroll
      for (int j = 0; j < 4; ++j) {
        const int m = m0 + wm * 64 + i * 16 + quad * 4;
        const int n = n0 + wn * 64 + j * 16 + l16;
        const int b = m >> 11, s = m & 2047;
        const int h = n >> 6, dh = n & 63;
        ushort4 pk = make_ushort4(f2bf(acc[i][j][0]), f2bf(acc[i][j][1]),
                                  f2bf(acc[i][j][2]), f2bf(acc[i][j][3]));
        *(ushort4*)(out + (((size_t)(b * NH + h)) * DHD + dh) * S_LEN + s) = pk;
      }
  }
}

// ---------------- output projection GEMM -> f32 ----------------------------
__global__ __launch_bounds__(256) void gemm_out(const u16* __restrict__ A,
                                                const u16* __restrict__ Bw,
                                                float* __restrict__ out) {
  constexpr int K = 1024, N = 1024;
  __shared__ __align__(16) u16 Asm[128 * 32];
  __shared__ __align__(16) u16 Bsm[128 * 32];
  const int tid = threadIdx.x;
  const int wave = tid >> 6, lane = tid & 63;
  const int wm = wave >> 1, wn = wave & 1;
  const int quad = lane >> 4, l16 = lane & 15;
  const int m0 = blockIdx.y * 128, n0 = blockIdx.x * 128;
  const u16* Ag = A + (size_t)(m0 + (lane >> 2)) * K + (lane & 3) * 8;
  const u16* Bg = Bw + (size_t)(n0 + (lane >> 2)) * K + (lane & 3) * 8;

  f32x4 acc[4][4] = {};
  for (int k0 = 0; k0 < K; k0 += 32) {
#pragma unroll
    for (int c = 0; c < 2; ++c) {
      const int rbase = wave * 32 + c * 16;
      gld_lds16(Ag + (size_t)rbase * K + k0, Asm + rbase * 32);
      gld_lds16(Bg + (size_t)rbase * K + k0, Bsm + rbase * 32);
    }
    __syncthreads();
    bf16x8 af[4], bfv[4];
#pragma unroll
    for (int i = 0; i < 4; ++i)
      af[i] = *(const bf16x8*)(Asm + (wm * 64 + i * 16 + l16) * 32 + quad * 8);
#pragma unroll
    for (int j = 0; j < 4; ++j)
      bfv[j] = *(const bf16x8*)(Bsm + (wn * 64 + j * 16 + l16) * 32 + quad * 8);
#pragma unroll
    for (int i = 0; i < 4; ++i)
#pragma unroll
      for (int j = 0; j < 4; ++j)
        acc[i][j] = __builtin_amdgcn_mfma_f32_16x16x32_bf16(af[i], bfv[j],
                                                            acc[i][j], 0, 0, 0);
    __syncthreads();
  }
#pragma unroll
  for (int i = 0; i < 4; ++i)
#pragma unroll
    for (int j = 0; j < 4; ++j)
#pragma unroll
      for (int r = 0; r < 4; ++r) {
        const int m = m0 + wm * 64 + i * 16 + quad * 4 + r;
        const int n = n0 + wn * 64 + j * 16 + l16;
        out[(size_t)m * N + n] = acc[i][j][r];
      }
}

// ---------------- causal flash attention, BM=128, BK=64 --------------------
__global__ __launch_bounds__(256) void attn_kernel(const u16* __restrict__ Qw,
                                                   const u16* __restrict__ Kw,
                                                   const u16* __restrict__ Vw,
                                                   u16* __restrict__ Ow) {
  __shared__ __align__(16) u16 Ksm[64 * KPAD];      // [key][dh] padded
  __shared__ __align__(16) u16 Vsm[64 * KPAD];      // [dh][key] padded
  __shared__ __align__(16) u16 Psm[4 * 32 * PPAD];  // per-wave [32 q][64 key]
  const int tid = threadIdx.x;
  const int wave = tid >> 6, lane = tid & 63;
  const int quad = lane >> 4, l16 = lane & 15;
  const int qt = 15 - blockIdx.x, bh = blockIdx.y;
  const int q0 = qt * 128;
  const u16* Q = Qw + (size_t)bh * S_LEN * DHD;
  const u16* Kp = Kw + (size_t)bh * S_LEN * DHD;
  const u16* Vp = Vw + (size_t)bh * DHD * S_LEN;
  const int b = bh >> 4, h = bh & 15;
  u16* Pw = Psm + wave * (32 * PPAD);

  // Q A-frags for both m-halves, both 32-wide k chains
  bf16x8 aq[2][2];
#pragma unroll
  for (int f = 0; f < 2; ++f)
#pragma unroll
    for (int ch = 0; ch < 2; ++ch)
      aq[f][ch] = *(const bf16x8*)(Q +
          (size_t)(q0 + f * 64 + wave * 16 + l16) * DHD + ch * 32 + quad * 8);

  f32x4 oacc[2][4] = {};
  float l_lane[2][4] = {};
  const int ntile = 2 * qt + 2;

  // staging map: thread covers chunks (row, col) = (tid>>3 [+32], (tid&7)*8)
  const int srow = tid >> 3, scol = (tid & 7) * 8;
  uint4 kr[2], vr[2];
#pragma unroll
  for (int c = 0; c < 2; ++c) {
    kr[c] = *(const uint4*)(Kp + (size_t)(srow + c * 32) * DHD + scol);
    vr[c] = *(const uint4*)(Vp + (size_t)(srow + c * 32) * S_LEN + scol);
  }

  for (int t = 0; t < ntile; ++t) {
    const int k0 = t * 64;
    __syncthreads();  // previous tile's LDS reads complete
#pragma unroll
    for (int c = 0; c < 2; ++c) {
      *(uint4*)(Ksm + (srow + c * 32) * KPAD + scol) = kr[c];
      *(uint4*)(Vsm + (srow + c * 32) * KPAD + scol) = vr[c];
    }
    __syncthreads();
    if (t + 1 < ntile) {
      const int kn = k0 + 64;
#pragma unroll
      for (int c = 0; c < 2; ++c) {
        kr[c] = *(const uint4*)(Kp + (size_t)(kn + srow + c * 32) * DHD + scol);
        vr[c] = *(const uint4*)(Vp + (size_t)(srow + c * 32) * S_LEN + kn + scol);
      }
    }

#pragma unroll
    for (int f = 0; f < 2; ++f) {
      const int rmin = q0 + f * 64 + wave * 16;  // wave-uniform strip base
      if (k0 > rmin + 15) continue;              // fully masked: skip half
      const bool need_mask = (k0 + 63 > rmin);

      // S = Q K^T
      f32x4 sacc[4];
#pragma unroll
      for (int nt = 0; nt < 4; ++nt) {
        const bf16x8 b0 = *(const bf16x8*)(Ksm + (nt * 16 + l16) * KPAD + quad * 8);
        const bf16x8 b1 = *(const bf16x8*)(Ksm + (nt * 16 + l16) * KPAD + 32 + quad * 8);
        f32x4 z = {};
        z = __builtin_amdgcn_mfma_f32_16x16x32_bf16(aq[f][0], b0, z, 0, 0, 0);
        z = __builtin_amdgcn_mfma_f32_16x16x32_bf16(aq[f][1], b1, z, 0, 0, 0);
        sacc[nt] = z;
      }

      // p = exp(s/8 - 12) (uniform offset cancels in p/sum(p)); causal mask
#pragma unroll
      for (int r = 0; r < 4; ++r) {
        const int qr = rmin + quad * 4 + r;
#pragma unroll
        for (int nt = 0; nt < 4; ++nt) {
          float p = __expf(fmaf(sacc[nt][r], 0.125f, -12.0f));
          if (need_mask && (k0 + nt * 16 + l16 > qr)) p = 0.f;
          l_lane[f][r] += p;
          Pw[(f * 16 + quad * 4 + r) * PPAD + nt * 16 + l16] = f2bf_fast(p);
        }
      }

      // CROSS-LANE LDS round-trip: fence before reading other lanes' writes
      lds_wave_fence();

      // O += P V  (P C->A layout transform)
      const bf16x8 ap0 = *(const bf16x8*)(Pw + (f * 16 + l16) * PPAD + quad * 8);
      const bf16x8 ap1 = *(const bf16x8*)(Pw + (f * 16 + l16) * PPAD + 32 + quad * 8);
#pragma unroll
      for (int nt = 0; nt < 4; ++nt) {
        const bf16x8 bv0 = *(const bf16x8*)(Vsm + (nt * 16 + l16) * KPAD + quad * 8);
        const bf16x8 bv1 = *(const bf16x8*)(Vsm + (nt * 16 + l16) * KPAD + 32 + quad * 8);
        oacc[f][nt] = __builtin_amdgcn_mfma_f32_16x16x32_bf16(ap0, bv0, oacc[f][nt], 0, 0, 0);
        oacc[f][nt] = __builtin_amdgcn_mfma_f32_16x16x32_bf16(ap1, bv1, oacc[f][nt], 0, 0, 0);
      }
    }
  }

  // epilogue -> [b, s, h, dh] bf16
#pragma unroll
  for (int f = 0; f < 2; ++f)
#pragma unroll
    for (int r = 0; r < 4; ++r) {
      float l = l_lane[f][r];
#pragma unroll
      for (int off = 1; off < 16; off <<= 1) l += __shfl_xor(l, off);
      const float inv = 1.f / l;
      const int s = q0 + f * 64 + wave * 16 + quad * 4 + r;
#pragma unroll
      for (int nt = 0; nt < 4; ++nt) {
        const int dh = nt * 16 + l16;
        Ow[(((size_t)b * S_LEN + s) * NH + h) * DHD + dh] =
            f2bf(oacc[f][nt][r] * inv);
      }
    }
}

extern "C" void kernel_launch(void* const* d_in, const int* in_sizes, int n_in,
                              void* d_out, int out_size, void* d_ws, size_t ws_size,
                              hipStream_t stream) {
  const float* x  = (const float*)d_in[0];
  const float* wq = (const float*)d_in[1];
  const float* wk = (const float*)d_in[2];
  const float* wv = (const float*)d_in[3];
  const float* wo = (const float*)d_in[4];
  float* out = (float*)d_out;
  char* ws = (char*)d_ws;
  const size_t MB = 1024 * 1024;
  u16* xb  = (u16*)(ws);             // 8 MB  [4096][1024] bf16
  u16* wqb = (u16*)(ws + 8 * MB);    // 2 MB
  u16* wkb = (u16*)(ws + 10 * MB);   // 2 MB
  u16* wvb = (u16*)(ws + 12 * MB);   // 2 MB
  u16* wob = (u16*)(ws + 14 * MB);   // 2 MB
  u16* qws = (u16*)(ws + 16 * MB);   // 8 MB  [b,h,s,dh]
  u16* kws = (u16*)(ws + 24 * MB);   // 8 MB  [b,h,s,dh]
  u16* vws = (u16*)(ws + 32 * MB);   // 8 MB  [b,h,dh,s]
  u16* aws = (u16*)(ws + 40 * MB);   // 8 MB  [b,s,h,dh]

  cvt_all<<<8192, 256, 0, stream>>>(x, wq, wk, wv, wo, xb);
  gemm_qkv<<<dim3(24, 32), 256, 0, stream>>>(xb, wqb, wkb, wvb, qws, kws, vws);
  attn_kernel<<<dim3(16, 32), 256, 0, stream>>>(qws, kws, vws, aws);
  gemm_out<<<dim3(8, 32), 256, 0, stream>>>(aws, wob, out);
}

// Round 6
// 225.982 us; speedup vs baseline: 1.1784x; 1.1784x over previous
//
#include <hip/hip_runtime.h>

// MHA forward, MI355X/gfx950, bf16 MFMA pipeline. Round 6.
// x:[2,2048,1024] f32; w_q/k/v/o:[1024,1024] f32 (nn.Linear: y = x @ W^T)
// out:[2,2048,1024] f32.
//
// R6: attn rebuilt = R2's balanced pairing + R5's LDS padding/prefetch.
//  - pairs {i, 31-i} of 64-row q-tiles -> 512 blocks x uniform 33 k-tiles
//    (R3/R5 regression: unpaired grid had 2..32 tiles/block -> critical-path
//    imbalance, attn 2x slower despite fewer bank conflicts)
//  - BK=64; per-wave 16-row strip; tiles 64-aligned -> no divergent skips,
//    mask only on the block-uniform diagonal tile
//  - single wave-local fence per tile after all P writes (cross-lane LDS
//    round-trip needs compiler ordering pinned; DS ops in-order per wave)
//  - padded rows (72 u16) -> 2-way LDS conflicts (free, m136)

typedef __bf16 bf16x8 __attribute__((ext_vector_type(8)));
typedef float f32x4 __attribute__((ext_vector_type(4)));
typedef unsigned short u16;

#define S_LEN 2048
#define NH 16
#define DHD 64
#define KPAD 72   // u16 stride for Ksm/Vsm rows (64 cols + 8 pad, 144 B)
#define PPAD 72   // u16 stride for Psm rows

__device__ __forceinline__ u16 f2bf(float f) {
  unsigned u = __float_as_uint(f);
  u += 0x7fffu + ((u >> 16) & 1u);  // RNE
  return (u16)(u >> 16);
}
__device__ __forceinline__ u16 f2bf_fast(float f) {  // round-half-up
  return (u16)((__float_as_uint(f) + 0x8000u) >> 16);
}

// wave-local LDS write->read ordering fence (cross-lane exchange within wave)
__device__ __forceinline__ void lds_wave_fence() {
  __builtin_amdgcn_wave_barrier();
  asm volatile("s_waitcnt lgkmcnt(0)" ::: "memory");
  __builtin_amdgcn_wave_barrier();
}

__device__ __forceinline__ void gld_lds16(const void* g, void* l) {
  __builtin_amdgcn_global_load_lds(
      (const __attribute__((address_space(1))) void*)g,
      (__attribute__((address_space(3))) void*)l, 16, 0, 0);
}

// ---------------- fp32 -> bf16 convert, all 5 tensors ----------------------
__global__ __launch_bounds__(256) void cvt_all(const float* __restrict__ x,
                                               const float* __restrict__ wq,
                                               const float* __restrict__ wk,
                                               const float* __restrict__ wv,
                                               const float* __restrict__ wo,
                                               u16* __restrict__ dst) {
  const int i = (blockIdx.x * 256 + threadIdx.x) * 4;
  const float* src;
  int off;
  if (i < (4 << 20))      { src = x;  off = 0; }
  else if (i < (5 << 20)) { src = wq; off = 4 << 20; }
  else if (i < (6 << 20)) { src = wk; off = 5 << 20; }
  else if (i < (7 << 20)) { src = wv; off = 6 << 20; }
  else                    { src = wo; off = 7 << 20; }
  const float4 v = *(const float4*)(src + (i - off));
  *(ushort4*)(dst + i) = make_ushort4(f2bf(v.x), f2bf(v.y), f2bf(v.z), f2bf(v.w));
}

// ---------------- fused QKV projection GEMM --------------------------------
__global__ __launch_bounds__(256) void gemm_qkv(const u16* __restrict__ A,
                                                const u16* __restrict__ Wq,
                                                const u16* __restrict__ Wk,
                                                const u16* __restrict__ Wv,
                                                u16* __restrict__ Qo,
                                                u16* __restrict__ Ko,
                                                u16* __restrict__ Vo) {
  constexpr int K = 1024;
  __shared__ __align__(16) u16 Asm[128 * 32];
  __shared__ __align__(16) u16 Bsm[128 * 32];
  const int tid = threadIdx.x;
  const int wave = tid >> 6, lane = tid & 63;
  const int wm = wave >> 1, wn = wave & 1;
  const int quad = lane >> 4, l16 = lane & 15;
  const int m0 = blockIdx.y * 128;
  const int n0g = blockIdx.x * 128;
  const int wsel = n0g >> 10, n0 = n0g & 1023;
  const u16* Bw = (wsel == 0) ? Wq : (wsel == 1 ? Wk : Wv);
  u16* out = (wsel == 0) ? Qo : (wsel == 1 ? Ko : Vo);

  const u16* Ag = A + (size_t)(m0 + (lane >> 2)) * K + (lane & 3) * 8;
  const u16* Bg = Bw + (size_t)(n0 + (lane >> 2)) * K + (lane & 3) * 8;

  f32x4 acc[4][4] = {};
  for (int k0 = 0; k0 < K; k0 += 32) {
#pragma unroll
    for (int c = 0; c < 2; ++c) {
      const int rbase = wave * 32 + c * 16;
      gld_lds16(Ag + (size_t)rbase * K + k0, Asm + rbase * 32);
      gld_lds16(Bg + (size_t)rbase * K + k0, Bsm + rbase * 32);
    }
    __syncthreads();
    bf16x8 af[4], bfv[4];
#pragma unroll
    for (int i = 0; i < 4; ++i)
      af[i] = *(const bf16x8*)(Asm + (wm * 64 + i * 16 + l16) * 32 + quad * 8);
#pragma unroll
    for (int j = 0; j < 4; ++j)
      bfv[j] = *(const bf16x8*)(Bsm + (wn * 64 + j * 16 + l16) * 32 + quad * 8);
#pragma unroll
    for (int i = 0; i < 4; ++i)
#pragma unroll
      for (int j = 0; j < 4; ++j)
        acc[i][j] = __builtin_amdgcn_mfma_f32_16x16x32_bf16(af[i], bfv[j],
                                                            acc[i][j], 0, 0, 0);
    __syncthreads();
  }

  if (wsel < 2) {
#pragma unroll
    for (int i = 0; i < 4; ++i)
#pragma unroll
      for (int j = 0; j < 4; ++j)
#pragma unroll
        for (int r = 0; r < 4; ++r) {
          const int m = m0 + wm * 64 + i * 16 + quad * 4 + r;
          const int n = n0 + wn * 64 + j * 16 + l16;
          const int b = m >> 11, s = m & 2047;
          const int h = n >> 6, dh = n & 63;
          out[(((size_t)(b * NH + h)) * S_LEN + s) * DHD + dh] =
              f2bf(acc[i][j][r]);
        }
  } else {
    // V^T: pack 4 consecutive s into one ushort4 store
#pragma unroll
    for (int i = 0; i < 4; ++i)
#pragma unroll
      for (int j = 0; j < 4; ++j) {
        const int m = m0 + wm * 64 + i * 16 + quad * 4;
        const int n = n0 + wn * 64 + j * 16 + l16;
        const int b = m >> 11, s = m & 2047;
        const int h = n >> 6, dh = n & 63;
        ushort4 pk = make_ushort4(f2bf(acc[i][j][0]), f2bf(acc[i][j][1]),
                                  f2bf(acc[i][j][2]), f2bf(acc[i][j][3]));
        *(ushort4*)(out + (((size_t)(b * NH + h)) * DHD + dh) * S_LEN + s) = pk;
      }
  }
}

// ---------------- output projection GEMM -> f32 ----------------------------
__global__ __launch_bounds__(256) void gemm_out(const u16* __restrict__ A,
                                                const u16* __restrict__ Bw,
                                                float* __restrict__ out) {
  constexpr int K = 1024, N = 1024;
  __shared__ __align__(16) u16 Asm[128 * 32];
  __shared__ __align__(16) u16 Bsm[128 * 32];
  const int tid = threadIdx.x;
  const int wave = tid >> 6, lane = tid & 63;
  const int wm = wave >> 1, wn = wave & 1;
  const int quad = lane >> 4, l16 = lane & 15;
  const int m0 = blockIdx.y * 128, n0 = blockIdx.x * 128;
  const u16* Ag = A + (size_t)(m0 + (lane >> 2)) * K + (lane & 3) * 8;
  const u16* Bg = Bw + (size_t)(n0 + (lane >> 2)) * K + (lane & 3) * 8;

  f32x4 acc[4][4] = {};
  for (int k0 = 0; k0 < K; k0 += 32) {
#pragma unroll
    for (int c = 0; c < 2; ++c) {
      const int rbase = wave * 32 + c * 16;
      gld_lds16(Ag + (size_t)rbase * K + k0, Asm + rbase * 32);
      gld_lds16(Bg + (size_t)rbase * K + k0, Bsm + rbase * 32);
    }
    __syncthreads();
    bf16x8 af[4], bfv[4];
#pragma unroll
    for (int i = 0; i < 4; ++i)
      af[i] = *(const bf16x8*)(Asm + (wm * 64 + i * 16 + l16) * 32 + quad * 8);
#pragma unroll
    for (int j = 0; j < 4; ++j)
      bfv[j] = *(const bf16x8*)(Bsm + (wn * 64 + j * 16 + l16) * 32 + quad * 8);
#pragma unroll
    for (int i = 0; i < 4; ++i)
#pragma unroll
      for (int j = 0; j < 4; ++j)
        acc[i][j] = __builtin_amdgcn_mfma_f32_16x16x32_bf16(af[i], bfv[j],
                                                            acc[i][j], 0, 0, 0);
    __syncthreads();
  }
#pragma unroll
  for (int i = 0; i < 4; ++i)
#pragma unroll
    for (int j = 0; j < 4; ++j)
#pragma unroll
      for (int r = 0; r < 4; ++r) {
        const int m = m0 + wm * 64 + i * 16 + quad * 4 + r;
        const int n = n0 + wn * 64 + j * 16 + l16;
        out[(size_t)m * N + n] = acc[i][j][r];
      }
}

// ---------------- causal flash attention, BM=64, BK=64, paired -------------
// grid (16, 32): block handles q-tiles {pairi, 31-pairi} (64 rows each),
// uniform 33 k-tiles/block. 4 waves x 16 q-rows. K/V staged via VGPR ->
// padded LDS with next-tile register prefetch. Fixed-offset softmax
// p = exp(s/8 - 12) (uniform offset cancels in p/sum p).
__global__ __launch_bounds__(256) void attn_kernel(const u16* __restrict__ Qw,
                                                   const u16* __restrict__ Kw,
                                                   const u16* __restrict__ Vw,
                                                   u16* __restrict__ Ow) {
  __shared__ __align__(16) u16 Ksm[64 * KPAD];      // [key][dh] padded
  __shared__ __align__(16) u16 Vsm[64 * KPAD];      // [dh][key] padded
  __shared__ __align__(16) u16 Psm[4 * 16 * PPAD];  // per-wave [16 q][64 key]
  const int tid = threadIdx.x;
  const int wave = tid >> 6, lane = tid & 63;
  const int quad = lane >> 4, l16 = lane & 15;
  const int pairi = blockIdx.x, bh = blockIdx.y;
  const u16* Q = Qw + (size_t)bh * S_LEN * DHD;
  const u16* Kp = Kw + (size_t)bh * S_LEN * DHD;
  const u16* Vp = Vw + (size_t)bh * DHD * S_LEN;
  const int b = bh >> 4, h = bh & 15;
  u16* Pw = Psm + wave * (16 * PPAD);

  // staging map: thread t covers (row = t>>3 [+32], col = (t&7)*8), 16B each
  const int srow = tid >> 3, scol = (tid & 7) * 8;

  for (int tsel = 0; tsel < 2; ++tsel) {
    const int qt = tsel ? (31 - pairi) : pairi;
    const int q0 = qt * 64;
    const int rmin = q0 + wave * 16;

    const bf16x8 aq0 =
        *(const bf16x8*)(Q + (size_t)(rmin + l16) * DHD + quad * 8);
    const bf16x8 aq1 =
        *(const bf16x8*)(Q + (size_t)(rmin + l16) * DHD + 32 + quad * 8);

    f32x4 oacc[4] = {};
    float l_lane[4] = {0.f, 0.f, 0.f, 0.f};

    uint4 kr[2], vr[2];
#pragma unroll
    for (int c = 0; c < 2; ++c) {
      kr[c] = *(const uint4*)(Kp + (size_t)(srow + c * 32) * DHD + scol);
      vr[c] = *(const uint4*)(Vp + (size_t)(srow + c * 32) * S_LEN + scol);
    }

    for (int t = 0; t <= qt; ++t) {
      const int k0 = t * 64;
      __syncthreads();  // previous tile's LDS reads complete
#pragma unroll
      for (int c = 0; c < 2; ++c) {
        *(uint4*)(Ksm + (srow + c * 32) * KPAD + scol) = kr[c];
        *(uint4*)(Vsm + (srow + c * 32) * KPAD + scol) = vr[c];
      }
      __syncthreads();
      if (t < qt) {
        const int kn = k0 + 64;
#pragma unroll
        for (int c = 0; c < 2; ++c) {
          kr[c] = *(const uint4*)(Kp + (size_t)(kn + srow + c * 32) * DHD + scol);
          vr[c] = *(const uint4*)(Vp + (size_t)(srow + c * 32) * S_LEN + kn + scol);
        }
      }

      // S = Q K^T : 4 key n-tiles, dh=64 as 2-chain
      f32x4 sacc[4];
#pragma unroll
      for (int nt = 0; nt < 4; ++nt) {
        const bf16x8 b0 = *(const bf16x8*)(Ksm + (nt * 16 + l16) * KPAD + quad * 8);
        const bf16x8 b1 = *(const bf16x8*)(Ksm + (nt * 16 + l16) * KPAD + 32 + quad * 8);
        f32x4 z = {};
        z = __builtin_amdgcn_mfma_f32_16x16x32_bf16(aq0, b0, z, 0, 0, 0);
        z = __builtin_amdgcn_mfma_f32_16x16x32_bf16(aq1, b1, z, 0, 0, 0);
        sacc[nt] = z;
      }

      // p = exp(s/8 - 12); mask only on the diagonal tile (block-uniform)
      const bool diag = (t == qt);
#pragma unroll
      for (int r = 0; r < 4; ++r) {
        const int rq = wave * 16 + quad * 4 + r;  // row within q-tile
#pragma unroll
        for (int nt = 0; nt < 4; ++nt) {
          float p = __expf(fmaf(sacc[nt][r], 0.125f, -12.0f));
          if (diag && (nt * 16 + l16 > rq)) p = 0.f;
          l_lane[r] += p;
          Pw[(quad * 4 + r) * PPAD + nt * 16 + l16] = f2bf_fast(p);
        }
      }

      // cross-lane LDS round-trip: pin ordering, single fence per tile
      lds_wave_fence();

      // O += P V
      const bf16x8 ap0 = *(const bf16x8*)(Pw + l16 * PPAD + quad * 8);
      const bf16x8 ap1 = *(const bf16x8*)(Pw + l16 * PPAD + 32 + quad * 8);
#pragma unroll
      for (int nt = 0; nt < 4; ++nt) {
        const bf16x8 bv0 = *(const bf16x8*)(Vsm + (nt * 16 + l16) * KPAD + quad * 8);
        const bf16x8 bv1 = *(const bf16x8*)(Vsm + (nt * 16 + l16) * KPAD + 32 + quad * 8);
        oacc[nt] = __builtin_amdgcn_mfma_f32_16x16x32_bf16(ap0, bv0, oacc[nt], 0, 0, 0);
        oacc[nt] = __builtin_amdgcn_mfma_f32_16x16x32_bf16(ap1, bv1, oacc[nt], 0, 0, 0);
      }
    }

    // epilogue -> [b, s, h, dh] bf16
#pragma unroll
    for (int r = 0; r < 4; ++r) {
      float l = l_lane[r];
#pragma unroll
      for (int off = 1; off < 16; off <<= 1) l += __shfl_xor(l, off);
      const float inv = 1.f / l;
      const int s = rmin + quad * 4 + r;
#pragma unroll
      for (int nt = 0; nt < 4; ++nt) {
        const int dh = nt * 16 + l16;
        Ow[(((size_t)b * S_LEN + s) * NH + h) * DHD + dh] =
            f2bf(oacc[nt][r] * inv);
      }
    }
  }
}

extern "C" void kernel_launch(void* const* d_in, const int* in_sizes, int n_in,
                              void* d_out, int out_size, void* d_ws, size_t ws_size,
                              hipStream_t stream) {
  const float* x  = (const float*)d_in[0];
  const float* wq = (const float*)d_in[1];
  const float* wk = (const float*)d_in[2];
  const float* wv = (const float*)d_in[3];
  const float* wo = (const float*)d_in[4];
  float* out = (float*)d_out;
  char* ws = (char*)d_ws;
  const size_t MB = 1024 * 1024;
  u16* xb  = (u16*)(ws);             // 8 MB  [4096][1024] bf16
  u16* wqb = (u16*)(ws + 8 * MB);    // 2 MB
  u16* wkb = (u16*)(ws + 10 * MB);   // 2 MB
  u16* wvb = (u16*)(ws + 12 * MB);   // 2 MB
  u16* wob = (u16*)(ws + 14 * MB);   // 2 MB
  u16* qws = (u16*)(ws + 16 * MB);   // 8 MB  [b,h,s,dh]
  u16* kws = (u16*)(ws + 24 * MB);   // 8 MB  [b,h,s,dh]
  u16* vws = (u16*)(ws + 32 * MB);   // 8 MB  [b,h,dh,s]
  u16* aws = (u16*)(ws + 40 * MB);   // 8 MB  [b,s,h,dh]

  cvt_all<<<8192, 256, 0, stream>>>(x, wq, wk, wv, wo, xb);
  gemm_qkv<<<dim3(24, 32), 256, 0, stream>>>(xb, wqb, wkb, wvb, qws, kws, vws);
  attn_kernel<<<dim3(16, 32), 256, 0, stream>>>(qws, kws, vws, aws);
  gemm_out<<<dim3(8, 32), 256, 0, stream>>>(aws, wob, out);
}